// Round 3
// baseline (629.131 us; speedup 1.0000x reference)
//
#include <hip/hip_runtime.h>
#include <stdint.h>

#define K_DIM 1024
#define N_DIM 1024
#define M_MAX 65536

// GEMM geometry: 256x256 tile, BK=32, 8 waves (2M x 4N), 512 threads,
// 4-stage LDS ring buffer (128 KiB) -> 3-tile prefetch depth, vmcnt(6) gate.
#define BM 256
#define BN 256
#define BK 32
#define NKT (K_DIM / BK)      // 32 k-tiles
#define NBUF 4
#define A_TILE (BM * BK)      // 8192 ushorts = 16 KiB
#define B_TILE (BN * BK)

typedef __attribute__((ext_vector_type(8))) __bf16 bf16x8;
typedef __attribute__((ext_vector_type(4))) float f32x4;

// Static device storage (fully rewritten every call; BSS, no load-time cost)
__device__ __align__(16) unsigned short g_wq[N_DIM * K_DIM];          // ternary W as bf16 bits
__device__ __align__(16) unsigned short g_xq[(size_t)M_MAX * K_DIM];  // x as bf16 bits (128 MB)
__device__ double g_partial[256];
__device__ float g_scale;

__device__ __forceinline__ unsigned int pack_bf16(float hi, float lo) {
  // (trunc_bf16(hi) << 16) | trunc_bf16(lo) in one v_perm_b32
  return __builtin_amdgcn_perm(__float_as_uint(hi), __float_as_uint(lo), 0x07060302u);
}

// ---- Kernel 1: partial sums of |w| (double accumulation, deterministic) ----
__global__ void absum_kernel(const float* __restrict__ w) {
  const int tid = threadIdx.x, bid = blockIdx.x;
  const float4* w4 = (const float4*)w;  // 262144 float4s total
  double s = 0.0;
#pragma unroll
  for (int i = 0; i < 4; i++) {
    float4 v = w4[bid * 1024 + i * 256 + tid];
    s += (double)fabsf(v.x) + (double)fabsf(v.y) + (double)fabsf(v.z) + (double)fabsf(v.w);
  }
#pragma unroll
  for (int o = 32; o > 0; o >>= 1) s += __shfl_down(s, o);
  __shared__ double sm[4];
  if ((tid & 63) == 0) sm[tid >> 6] = s;
  __syncthreads();
  if (tid == 0) g_partial[bid] = sm[0] + sm[1] + sm[2] + sm[3];
}

// ---- Kernel 2: final reduce -> scale = max(mean|w|, 1e-5) ----
__global__ void scale_kernel() {
  const int tid = threadIdx.x;
  double v = g_partial[tid];
#pragma unroll
  for (int o = 32; o > 0; o >>= 1) v += __shfl_down(v, o);
  __shared__ double sm[4];
  if ((tid & 63) == 0) sm[tid >> 6] = v;
  __syncthreads();
  if (tid == 0) {
    double total = sm[0] + sm[1] + sm[2] + sm[3];
    double mean = total * (1.0 / 1048576.0);  // exact pow2 divide
    g_scale = (float)fmax(mean, 1e-5);
  }
}

// ---- Kernel 3: quantize W -> ternary bf16 {-1,0,1} (exact in bf16) ----
__global__ void quant_kernel(const float* __restrict__ w) {
  const int idx = blockIdx.x * 256 + threadIdx.x;  // x4 floats
  const float s = g_scale;
  float4 v = ((const float4*)w)[idx];
  float q0 = fminf(1.f, fmaxf(-1.f, rintf(v.x / s)));
  float q1 = fminf(1.f, fmaxf(-1.f, rintf(v.y / s)));
  float q2 = fminf(1.f, fmaxf(-1.f, rintf(v.z / s)));
  float q3 = fminf(1.f, fmaxf(-1.f, rintf(v.w / s)));
  ushort4 o;
  o.x = (unsigned short)(__float_as_uint(q0) >> 16);
  o.y = (unsigned short)(__float_as_uint(q1) >> 16);
  o.z = (unsigned short)(__float_as_uint(q2) >> 16);
  o.w = (unsigned short)(__float_as_uint(q3) >> 16);
  ((ushort4*)g_wq)[idx] = o;
}

// ---- Kernel 4: convert x fp32 -> bf16 (truncation, streaming) ----
__global__ __launch_bounds__(256) void convert_x(const float* __restrict__ x) {
  const size_t t = (size_t)blockIdx.x * 256 + threadIdx.x;  // 8 floats per thread
  const float4* x4 = (const float4*)x;
  float4 a = x4[t * 2];
  float4 b = x4[t * 2 + 1];
  uint4 o;
  o.x = pack_bf16(a.y, a.x);
  o.y = pack_bf16(a.w, a.z);
  o.z = pack_bf16(b.y, b.x);
  o.w = pack_bf16(b.w, b.z);
  ((uint4*)g_xq)[t] = o;
}

// ---- Kernel 5: GEMM  C[M,N] = (Aq[M,K] @ Wq[N,K]^T) * scale ----
// Phase-pipelined schedule: per K-tile two {mem-window -> barrier -> pure
// 16-MFMA window -> barrier} phases; every MFMA cluster's LDS frags were
// issued one phase earlier (ping-pong register sets, 2-tile unroll).
// 4-deep ring, vmcnt(6) gate; verified source-side swizzle (0 conflicts).
__global__ __launch_bounds__(512, 2) void bitlinear_gemm(float* __restrict__ C) {
  __shared__ __align__(16) unsigned short As[NBUF * A_TILE];  // 64 KiB
  __shared__ __align__(16) unsigned short Bs[NBUF * B_TILE];  // 64 KiB

  const int tid  = threadIdx.x;
  const int lane = tid & 63;
  const int wave = tid >> 6;   // 0..7
  const int wm   = wave >> 2;  // 0..1  -> 128 rows each
  const int wn   = wave & 3;   // 0..3  -> 64 cols each
  const int lm   = lane & 15;
  const int lq   = lane >> 4;

  // XCD-locality swizzle (nwg = 1024, divisible by 8 -> bijective)
  const int b       = blockIdx.x;
  const int cpx     = (int)(gridDim.x >> 3);
  const int logical = (b & 7) * cpx + (b >> 3);
  const int mt      = logical >> 2;  // N_DIM/BN == 4 n-tiles
  const int nt      = logical & 3;
  const int m0      = mt * BM;
  const int n0      = nt * BN;

  f32x4 acc[8][4];
#pragma unroll
  for (int i = 0; i < 8; i++)
#pragma unroll
    for (int j = 0; j < 4; j++) acc[i][j] = (f32x4){0.f, 0.f, 0.f, 0.f};

  // --- Staging geometry (identical to verified R1 kernel) ---------------
  const int cswz = ((lane & 3) ^ ((lane >> 3) & 3)) * 8;  // ushort offset
  const unsigned short* aSrc =
      g_xq + (size_t)(m0 + wave * 32 + (lane >> 2)) * K_DIM + cswz;
  const unsigned short* bSrc =
      g_wq + (size_t)(n0 + wave * 32 + (lane >> 2)) * K_DIM + cswz;
  const int ldsDst = wave * 32 * BK;  // ushort offset of this wave's rows

#define STAGE_A(tt, bb)                                                        \
  do {                                                                         \
    const unsigned short* s_ = aSrc + (tt) * BK;                               \
    unsigned short* d_ = &As[(bb) * A_TILE + ldsDst];                          \
    __builtin_amdgcn_global_load_lds(                                          \
        (const __attribute__((address_space(1))) unsigned int*)s_,             \
        (__attribute__((address_space(3))) unsigned int*)d_, 16, 0, 0);        \
    __builtin_amdgcn_global_load_lds(                                          \
        (const __attribute__((address_space(1))) unsigned int*)(s_ + 16 * K_DIM), \
        (__attribute__((address_space(3))) unsigned int*)(d_ + 16 * BK), 16, 0, 0); \
  } while (0)

#define STAGE_B(tt, bb)                                                        \
  do {                                                                         \
    const unsigned short* s_ = bSrc + (tt) * BK;                               \
    unsigned short* d_ = &Bs[(bb) * B_TILE + ldsDst];                          \
    __builtin_amdgcn_global_load_lds(                                          \
        (const __attribute__((address_space(1))) unsigned int*)s_,             \
        (__attribute__((address_space(3))) unsigned int*)d_, 16, 0, 0);        \
    __builtin_amdgcn_global_load_lds(                                          \
        (const __attribute__((address_space(1))) unsigned int*)(s_ + 16 * K_DIM), \
        (__attribute__((address_space(3))) unsigned int*)(d_ + 16 * BK), 16, 0, 0); \
  } while (0)

  // --- LDS read addressing (swizzled; verified: 0 bank conflicts) --------
  const int xorc = (((lm >> 1) & 3) ^ lq) * 8;
  const int aRd  = (wm * 128 + lm) * BK + xorc;
  const int bRd  = (wn * 64 + lm) * BK + xorc;

  // --- Prologue: stage tiles 0,1,2; gate tile 0; read its phase-A frags --
  STAGE_A(0, 0);
  STAGE_B(0, 0);
  STAGE_A(1, 1);
  STAGE_B(1, 1);
  STAGE_A(2, 2);
  STAGE_B(2, 2);
  asm volatile("s_waitcnt vmcnt(8)\n\ts_barrier" ::: "memory");  // tile 0 landed

  bf16x8 afE[4], bfE[4], afO[4], bfO[4];
  {
    const unsigned short* Ab0 = &As[aRd];
    const unsigned short* Bb0 = &Bs[bRd];
#pragma unroll
    for (int mf = 0; mf < 4; ++mf) afE[mf] = *(const bf16x8*)(Ab0 + mf * 16 * BK);
#pragma unroll
    for (int nf = 0; nf < 4; ++nf) bfE[nf] = *(const bf16x8*)(Bb0 + nf * 16 * BK);
  }

#pragma unroll 1
  for (int tt = 0; tt < NKT; tt += 2) {
    const int cb = tt & 3;  // even-tile buf (0 or 2)

    // ================= tile tt (even): frags afE/bfE ====================
    {
      const unsigned short* Ab = &As[cb * A_TILE + aRd];
      const unsigned short* Bb = &Bs[cb * B_TILE + bRd];

      // -- Phase A (mem window): a2 frags + STAGE_A(tt+3) + vm-gate ------
      bf16x8 a2[4];
#pragma unroll
      for (int mf = 0; mf < 4; ++mf)
        a2[mf] = *(const bf16x8*)(Ab + (mf + 4) * 16 * BK);
      if (tt < 29) STAGE_A(tt + 3, cb ^ 3);
      // gate: tile tt+1 landed (outstanding allowed: t+2's 4 + t+3's A 2)
      if (tt < 30)
        asm volatile("s_waitcnt vmcnt(6)\n\ts_barrier" ::: "memory");
      else
        asm volatile("s_waitcnt vmcnt(0)\n\ts_barrier" ::: "memory");

      __builtin_amdgcn_s_setprio(1);
#pragma unroll
      for (int mf = 0; mf < 4; ++mf)
#pragma unroll
        for (int nf = 0; nf < 4; ++nf)
          acc[mf][nf] = __builtin_amdgcn_mfma_f32_16x16x32_bf16(
              afE[mf], bfE[nf], acc[mf][nf], 0, 0, 0);
      __builtin_amdgcn_s_setprio(0);
      asm volatile("s_barrier" ::: "memory");

      // -- Phase B (mem window): next tile's phase-A frags + STAGE_B -----
      {
        const int cn = cb + 1;  // (tt+1)&3
        const unsigned short* AbN = &As[cn * A_TILE + aRd];
        const unsigned short* BbN = &Bs[cn * B_TILE + bRd];
#pragma unroll
        for (int mf = 0; mf < 4; ++mf)
          afO[mf] = *(const bf16x8*)(AbN + mf * 16 * BK);
#pragma unroll
        for (int nf = 0; nf < 4; ++nf)
          bfO[nf] = *(const bf16x8*)(BbN + nf * 16 * BK);
      }
      if (tt < 29) STAGE_B(tt + 3, cb ^ 3);
      asm volatile("s_barrier" ::: "memory");

      __builtin_amdgcn_s_setprio(1);
#pragma unroll
      for (int mf = 0; mf < 4; ++mf)
#pragma unroll
        for (int nf = 0; nf < 4; ++nf)
          acc[mf + 4][nf] = __builtin_amdgcn_mfma_f32_16x16x32_bf16(
              a2[mf], bfE[nf], acc[mf + 4][nf], 0, 0, 0);
      __builtin_amdgcn_s_setprio(0);
      asm volatile("s_barrier" ::: "memory");
    }

    // ================= tile tt+1 (odd): frags afO/bfO ===================
    {
      const int cu = cb + 1;  // odd-tile buf (1 or 3)
      const unsigned short* Ab = &As[cu * A_TILE + aRd];
      const unsigned short* Bb = &Bs[cu * B_TILE + bRd];

      // -- Phase A: a2 frags + STAGE_A(tt+4) + vm-gate -------------------
      bf16x8 a2[4];
#pragma unroll
      for (int mf = 0; mf < 4; ++mf)
        a2[mf] = *(const bf16x8*)(Ab + (mf + 4) * 16 * BK);
      if (tt < 28) STAGE_A(tt + 4, cb);
      // gate: tile tt+2 landed. N: tt<=26 -> 6, tt==28 -> 4, tt==30 -> 0
      if (tt < 28)
        asm volatile("s_waitcnt vmcnt(6)\n\ts_barrier" ::: "memory");
      else if (tt < 30)
        asm volatile("s_waitcnt vmcnt(4)\n\ts_barrier" ::: "memory");
      else
        asm volatile("s_waitcnt vmcnt(0)\n\ts_barrier" ::: "memory");

      __builtin_amdgcn_s_setprio(1);
#pragma unroll
      for (int mf = 0; mf < 4; ++mf)
#pragma unroll
        for (int nf = 0; nf < 4; ++nf)
          acc[mf][nf] = __builtin_amdgcn_mfma_f32_16x16x32_bf16(
              afO[mf], bfO[nf], acc[mf][nf], 0, 0, 0);
      __builtin_amdgcn_s_setprio(0);
      asm volatile("s_barrier" ::: "memory");

      // -- Phase B: tile tt+2's phase-A frags + STAGE_B(tt+4) ------------
      if (tt < 30) {
        const int cn = cb ^ 2;  // (tt+2)&3
        const unsigned short* AbN = &As[cn * A_TILE + aRd];
        const unsigned short* BbN = &Bs[cn * B_TILE + bRd];
#pragma unroll
        for (int mf = 0; mf < 4; ++mf)
          afE[mf] = *(const bf16x8*)(AbN + mf * 16 * BK);
#pragma unroll
        for (int nf = 0; nf < 4; ++nf)
          bfE[nf] = *(const bf16x8*)(BbN + nf * 16 * BK);
      }
      if (tt < 28) STAGE_B(tt + 4, cb);
      asm volatile("s_barrier" ::: "memory");

      __builtin_amdgcn_s_setprio(1);
#pragma unroll
      for (int mf = 0; mf < 4; ++mf)
#pragma unroll
        for (int nf = 0; nf < 4; ++nf)
          acc[mf + 4][nf] = __builtin_amdgcn_mfma_f32_16x16x32_bf16(
              a2[mf], bfO[nf], acc[mf + 4][nf], 0, 0, 0);
      __builtin_amdgcn_s_setprio(0);
      asm volatile("s_barrier" ::: "memory");
    }
  }
#undef STAGE_A
#undef STAGE_B

  // Epilogue: C/D layout col=lane&15, row=(lane>>4)*4+r; apply scale here
  const float s    = g_scale;
  const int   crow = m0 + wm * 128 + lq * 4;
  const int   ccol = n0 + wn * 64 + lm;
#pragma unroll
  for (int mf = 0; mf < 8; ++mf) {
#pragma unroll
    for (int nf = 0; nf < 4; ++nf) {
#pragma unroll
      for (int r = 0; r < 4; ++r) {
        C[(size_t)(crow + mf * 16 + r) * N_DIM + (ccol + nf * 16)] =
            acc[mf][nf][r] * s;
      }
    }
  }
}

extern "C" void kernel_launch(void* const* d_in, const int* in_sizes, int n_in,
                              void* d_out, int out_size, void* d_ws, size_t ws_size,
                              hipStream_t stream) {
  const float* x = (const float*)d_in[0];   // [M, 1024] fp32
  const float* w = (const float*)d_in[1];   // [1024, 1024] fp32
  float* out = (float*)d_out;               // [M, 1024] fp32
  const int M = in_sizes[0] / K_DIM;        // 65536

  hipLaunchKernelGGL(absum_kernel, dim3(256), dim3(256), 0, stream, w);
  hipLaunchKernelGGL(scale_kernel, dim3(1), dim3(256), 0, stream);
  hipLaunchKernelGGL(quant_kernel, dim3(1024), dim3(256), 0, stream, w);
  hipLaunchKernelGGL(convert_x, dim3((unsigned)((size_t)M * K_DIM / 8 / 256)), dim3(256), 0,
                     stream, x);
  hipLaunchKernelGGL(bitlinear_gemm,
                     dim3((unsigned)(((size_t)M / BM) * (N_DIM / BN))),
                     dim3(512), 0, stream, out);
}

// Round 4
// 565.905 us; speedup vs baseline: 1.1117x; 1.1117x over previous
//
#include <hip/hip_runtime.h>
#include <stdint.h>

#define K_DIM 1024
#define N_DIM 1024

// GEMM geometry: 256x256 tile, BK=32, 8 waves (2M x 4N), 512 threads,
// 3-stage LDS ring buffer (96 KiB), one vm-gate per K-tile (R1 schedule).
// A (x, fp32) is reg-staged + converted to bf16 in-kernel (convert_x fused).
#define BM 256
#define BN 256
#define BK 32
#define NKT (K_DIM / BK)      // 32 k-tiles
#define NBUF 3
#define A_TILE (BM * BK)      // 8192 ushorts = 16 KiB
#define B_TILE (BN * BK)

typedef __attribute__((ext_vector_type(8))) __bf16 bf16x8;
typedef __attribute__((ext_vector_type(4))) float f32x4;

// Static device storage (fully rewritten every call; BSS, no load-time cost)
__device__ __align__(16) unsigned short g_wq[N_DIM * K_DIM];  // ternary W as bf16 bits
__device__ double g_partial[256];
__device__ float g_scale;

__device__ __forceinline__ unsigned int pack_bf16(float hi, float lo) {
  // (trunc_bf16(hi) << 16) | trunc_bf16(lo) in one v_perm_b32
  return __builtin_amdgcn_perm(__float_as_uint(hi), __float_as_uint(lo), 0x07060302u);
}

// ---- Kernel 1: partial sums of |w| (double accumulation, deterministic) ----
__global__ void absum_kernel(const float* __restrict__ w) {
  const int tid = threadIdx.x, bid = blockIdx.x;
  const float4* w4 = (const float4*)w;  // 262144 float4s total
  double s = 0.0;
#pragma unroll
  for (int i = 0; i < 4; i++) {
    float4 v = w4[bid * 1024 + i * 256 + tid];
    s += (double)fabsf(v.x) + (double)fabsf(v.y) + (double)fabsf(v.z) + (double)fabsf(v.w);
  }
#pragma unroll
  for (int o = 32; o > 0; o >>= 1) s += __shfl_down(s, o);
  __shared__ double sm[4];
  if ((tid & 63) == 0) sm[tid >> 6] = s;
  __syncthreads();
  if (tid == 0) g_partial[bid] = sm[0] + sm[1] + sm[2] + sm[3];
}

// ---- Kernel 2: final reduce -> scale = max(mean|w|, 1e-5) ----
__global__ void scale_kernel() {
  const int tid = threadIdx.x;
  double v = g_partial[tid];
#pragma unroll
  for (int o = 32; o > 0; o >>= 1) v += __shfl_down(v, o);
  __shared__ double sm[4];
  if ((tid & 63) == 0) sm[tid >> 6] = v;
  __syncthreads();
  if (tid == 0) {
    double total = sm[0] + sm[1] + sm[2] + sm[3];
    double mean = total * (1.0 / 1048576.0);  // exact pow2 divide
    g_scale = (float)fmax(mean, 1e-5);
  }
}

// ---- Kernel 3: quantize W -> ternary bf16 {-1,0,1} (exact in bf16) ----
__global__ void quant_kernel(const float* __restrict__ w) {
  const int idx = blockIdx.x * 256 + threadIdx.x;  // x4 floats
  const float s = g_scale;
  float4 v = ((const float4*)w)[idx];
  float q0 = fminf(1.f, fmaxf(-1.f, rintf(v.x / s)));
  float q1 = fminf(1.f, fmaxf(-1.f, rintf(v.y / s)));
  float q2 = fminf(1.f, fmaxf(-1.f, rintf(v.z / s)));
  float q3 = fminf(1.f, fmaxf(-1.f, rintf(v.w / s)));
  ushort4 o;
  o.x = (unsigned short)(__float_as_uint(q0) >> 16);
  o.y = (unsigned short)(__float_as_uint(q1) >> 16);
  o.z = (unsigned short)(__float_as_uint(q2) >> 16);
  o.w = (unsigned short)(__float_as_uint(q3) >> 16);
  ((ushort4*)g_wq)[idx] = o;
}

// ---- Kernel 4: GEMM  C[M,N] = (bf16(x)[M,K] @ Wq[N,K]^T) * scale ----
// R1 schedule (one vmcnt-counted gate + barrier per K-tile) with fused
// fp32->bf16 A-staging: global fp32 loads -> v_perm pack -> swizzled
// ds_write_b128. B stays on the verified global_load_lds + source-permute
// swizzle path (0 bank conflicts measured).
__global__ __launch_bounds__(512, 2) void bitlinear_gemm(const float* __restrict__ x,
                                                         float* __restrict__ C) {
  __shared__ __align__(16) unsigned short As[NBUF * A_TILE];  // 48 KiB
  __shared__ __align__(16) unsigned short Bs[NBUF * B_TILE];  // 48 KiB

  const int tid  = threadIdx.x;
  const int lane = tid & 63;
  const int wave = tid >> 6;   // 0..7
  const int wm   = wave >> 2;  // 0..1  -> 128 rows each
  const int wn   = wave & 3;   // 0..3  -> 64 cols each
  const int lm   = lane & 15;
  const int lq   = lane >> 4;

  // XCD-locality swizzle (nwg = 1024, divisible by 8 -> bijective):
  // 4 consecutive logical blocks (one XCD) share one A-panel (fp32 panel =
  // 1 MB, L2-resident) and sweep the 4 n-tiles.
  const int b       = blockIdx.x;
  const int cpx     = (int)(gridDim.x >> 3);
  const int logical = (b & 7) * cpx + (b >> 3);
  const int mt      = logical >> 2;  // N_DIM/BN == 4 n-tiles
  const int nt      = logical & 3;
  const int m0      = mt * BM;
  const int n0      = nt * BN;

  f32x4 acc[8][4];
#pragma unroll
  for (int i = 0; i < 8; i++)
#pragma unroll
    for (int j = 0; j < 4; j++) acc[i][j] = (f32x4){0.f, 0.f, 0.f, 0.f};

  // --- B staging (verified R1 path): glds w=16, source-permute swizzle ---
  const int cswz = ((lane & 3) ^ ((lane >> 3) & 3)) * 8;  // ushort offset
  const unsigned short* bSrc =
      g_wq + (size_t)(n0 + wave * 32 + (lane >> 2)) * K_DIM + cswz;
  const int ldsDst = wave * 32 * BK;  // ushort offset of this wave's rows

#define STAGE_B(tt, bb)                                                        \
  do {                                                                         \
    const unsigned short* s_ = bSrc + (tt) * BK;                               \
    unsigned short* d_ = &Bs[(bb) * B_TILE + ldsDst];                          \
    __builtin_amdgcn_global_load_lds(                                          \
        (const __attribute__((address_space(1))) unsigned int*)s_,             \
        (__attribute__((address_space(3))) unsigned int*)d_, 16, 0, 0);        \
    __builtin_amdgcn_global_load_lds(                                          \
        (const __attribute__((address_space(1))) unsigned int*)(s_ + 16 * K_DIM), \
        (__attribute__((address_space(3))) unsigned int*)(d_ + 16 * BK), 16, 0, 0); \
  } while (0)

  // --- A staging (fused convert): lane l -> row wave*32+(l>>1), k-half l&1.
  // 4x global_load_dwordx4 fp32 (64 B) -> 8x v_perm -> 2x ds_write_b128 to
  // chunks (2h+i)^((row>>1)&3); write pattern is uniform 8 lanes/bank-quad
  // (minimal for b128) and matches the verified read-side XOR.
  const int arow = wave * 32 + (lane >> 1);       // row in tile
  const int ah   = lane & 1;                      // k-half (16 floats)
  const int aswz = (lane >> 2) & 3;               // ((arow>>1)&3)
  const float4* aGlb =
      (const float4*)(x + (size_t)(m0 + arow) * K_DIM + ah * 16);
  const int wo0 = arow * BK + (((2 * ah) ^ aswz) * 8);      // ushort offsets
  const int wo1 = arow * BK + (((2 * ah + 1) ^ aswz) * 8);

  float4 aR0, aR1, aR2, aR3;  // in-flight A k-window (16 floats)

#define LOAD_A(tt)                                                             \
  do {                                                                         \
    const float4* p_ = aGlb + (tt) * 8;                                        \
    aR0 = p_[0]; aR1 = p_[1]; aR2 = p_[2]; aR3 = p_[3];                        \
  } while (0)

#define CVT_WRITE_A(bb)                                                        \
  do {                                                                         \
    uint4 p0_, p1_;                                                            \
    p0_.x = pack_bf16(aR0.y, aR0.x); p0_.y = pack_bf16(aR0.w, aR0.z);          \
    p0_.z = pack_bf16(aR1.y, aR1.x); p0_.w = pack_bf16(aR1.w, aR1.z);          \
    p1_.x = pack_bf16(aR2.y, aR2.x); p1_.y = pack_bf16(aR2.w, aR2.z);          \
    p1_.z = pack_bf16(aR3.y, aR3.x); p1_.w = pack_bf16(aR3.w, aR3.z);          \
    *(uint4*)&As[(bb) * A_TILE + wo0] = p0_;                                   \
    *(uint4*)&As[(bb) * A_TILE + wo1] = p1_;                                   \
  } while (0)

  // --- LDS read addressing (swizzled; verified: 0 bank conflicts) --------
  const int xorc = (((lm >> 1) & 3) ^ lq) * 8;
  const int aRd  = (wm * 128 + lm) * BK + xorc;
  const int bRd  = (wn * 64 + lm) * BK + xorc;

  // --- Prologue ----------------------------------------------------------
  // Issue order: [A0 x4, B0 x2, A1 x4, B1 x2]; convert A0 (compiler emits
  // vmcnt(8)); gate: B0 done <=> vmcnt(6); lgkm drain publishes A0 writes.
  {
    float4 t0, t1, t2, t3;
    {
      const float4* p_ = aGlb;
      t0 = p_[0]; t1 = p_[1]; t2 = p_[2]; t3 = p_[3];
    }
    STAGE_B(0, 0);
    LOAD_A(1);
    STAGE_B(1, 1);
    uint4 p0_, p1_;
    p0_.x = pack_bf16(t0.y, t0.x); p0_.y = pack_bf16(t0.w, t0.z);
    p0_.z = pack_bf16(t1.y, t1.x); p0_.w = pack_bf16(t1.w, t1.z);
    p1_.x = pack_bf16(t2.y, t2.x); p1_.y = pack_bf16(t2.w, t2.z);
    p1_.z = pack_bf16(t3.y, t3.x); p1_.w = pack_bf16(t3.w, t3.z);
    *(uint4*)&As[wo0] = p0_;
    *(uint4*)&As[wo1] = p1_;
  }
  asm volatile("s_waitcnt vmcnt(6) lgkmcnt(0)\n\ts_barrier" ::: "memory");

  int buf = 0;
#pragma unroll 1
  for (int t = 0; t < NKT; ++t) {
    const unsigned short* Ab = &As[buf * A_TILE + aRd];
    const unsigned short* Bb = &Bs[buf * B_TILE + bRd];
    const int nbuf = (buf + 2 >= NBUF) ? buf + 2 - NBUF : buf + 2;
    const int wbuf = (buf + 1 == NBUF) ? 0 : buf + 1;

    // Phase 0: frag reads (B + A m0..3) -> 16 MFMA
    bf16x8 bfr[4], af[4];
#pragma unroll
    for (int nf = 0; nf < 4; ++nf) bfr[nf] = *(const bf16x8*)(Bb + nf * 16 * BK);
#pragma unroll
    for (int mf = 0; mf < 4; ++mf) af[mf] = *(const bf16x8*)(Ab + mf * 16 * BK);

    __builtin_amdgcn_s_setprio(1);
#pragma unroll
    for (int mf = 0; mf < 4; ++mf)
#pragma unroll
      for (int nf = 0; nf < 4; ++nf)
        acc[mf][nf] = __builtin_amdgcn_mfma_f32_16x16x32_bf16(af[mf], bfr[nf],
                                                              acc[mf][nf], 0, 0, 0);
    __builtin_amdgcn_s_setprio(0);

    // Phase 1: frag reads (A m4..7); A(t+1) convert+write; issue t+2; MFMA
    bf16x8 af2[4];
#pragma unroll
    for (int mf = 0; mf < 4; ++mf)
      af2[mf] = *(const bf16x8*)(Ab + (mf + 4) * 16 * BK);

    if (t < NKT - 1) CVT_WRITE_A(wbuf);   // A(t+1) -> buf (t+1)%3
    if (t < NKT - 2) {
      LOAD_A(t + 2);                      // fp32 loads for A(t+2)
      STAGE_B(t + 2, nbuf);               // glds for B(t+2)
    }

    __builtin_amdgcn_s_setprio(1);
#pragma unroll
    for (int mf = 0; mf < 4; ++mf)
#pragma unroll
      for (int nf = 0; nf < 4; ++nf)
        acc[mf + 4][nf] = __builtin_amdgcn_mfma_f32_16x16x32_bf16(
            af2[mf], bfr[nf], acc[mf + 4][nf], 0, 0, 0);
    __builtin_amdgcn_s_setprio(0);

    // Gate for tile t+1: B(t+1) landed (newer: A(t+2)x4 + B(t+2)x2 allowed
    // in flight); lgkm drain publishes this tile's A ds_writes.
    if (t < NKT - 2)
      asm volatile("s_waitcnt vmcnt(6) lgkmcnt(0)\n\ts_barrier" ::: "memory");
    else if (t < NKT - 1)
      asm volatile("s_waitcnt vmcnt(0) lgkmcnt(0)\n\ts_barrier" ::: "memory");

    buf = wbuf;
  }
#undef STAGE_B
#undef LOAD_A
#undef CVT_WRITE_A

  // Epilogue: C/D layout col=lane&15, row=(lane>>4)*4+r; apply scale here
  const float s    = g_scale;
  const int   crow = m0 + wm * 128 + lq * 4;
  const int   ccol = n0 + wn * 64 + lm;
#pragma unroll
  for (int mf = 0; mf < 8; ++mf) {
#pragma unroll
    for (int nf = 0; nf < 4; ++nf) {
#pragma unroll
      for (int r = 0; r < 4; ++r) {
        C[(size_t)(crow + mf * 16 + r) * N_DIM + (ccol + nf * 16)] =
            acc[mf][nf][r] * s;
      }
    }
  }
}

extern "C" void kernel_launch(void* const* d_in, const int* in_sizes, int n_in,
                              void* d_out, int out_size, void* d_ws, size_t ws_size,
                              hipStream_t stream) {
  const float* x = (const float*)d_in[0];   // [M, 1024] fp32
  const float* w = (const float*)d_in[1];   // [1024, 1024] fp32
  float* out = (float*)d_out;               // [M, 1024] fp32
  const int M = in_sizes[0] / K_DIM;        // 65536

  hipLaunchKernelGGL(absum_kernel, dim3(256), dim3(256), 0, stream, w);
  hipLaunchKernelGGL(scale_kernel, dim3(1), dim3(256), 0, stream);
  hipLaunchKernelGGL(quant_kernel, dim3(1024), dim3(256), 0, stream, w);
  hipLaunchKernelGGL(bitlinear_gemm,
                     dim3((unsigned)(((size_t)M / BM) * (N_DIM / BN))),
                     dim3(512), 0, stream, x, out);
}